// Round 13
// baseline (319.659 us; speedup 1.0000x reference)
//
#include <hip/hip_runtime.h>
#include <hip/hip_bf16.h>

// Problem constants: N=100000 nodes, E=1200000 edges, D=64, K=3 hops.
#define GN 100000
#define GE 1200000
#define GD 64
#define NG 256                 // col groups
#define CPG 391                // cols per group (256*391 = 100096 >= GN)
#define CAP 6144               // bucket capacity per group (mean 4688, std 68)

// ws_size ~256 MB (observed via harness re-poison fillBuffer WRITE_SIZE).
// This layout uses ~51 MB.
//
// CSR build: two-phase radix partition (r11) replaced scatter fill whose
// cross-XCD 64B-line writebacks cost ~1 per ENTRY (r7-r9). r12: gather
// restructured to predicated 16-edge blocks (dep rounds 6->3). r13: hop-1
// reads weight directly (X copy deleted); init fused into p1 dispatch.

// ---------------------------------------------------------------------------
// Runtime dtype detection. flags[0]=1 if weight/alpha bf16 else fp32.
// flags[1]=1 if edge_index int64 else int32.  Also zeroes gcount.
// ---------------------------------------------------------------------------
__global__ void detect_kernel(const void* __restrict__ w,
                              const void* __restrict__ edge,
                              int* __restrict__ flags, int* __restrict__ gcount) {
    __shared__ int s_badw, s_edgenz;
    if (threadIdx.x == 0) { s_badw = 0; s_edgenz = 0; }
    gcount[threadIdx.x] = 0;
    __syncthreads();
    const unsigned short* wh = (const unsigned short*)w;
    const unsigned int*   ei = (const unsigned int*)edge;
    int badw = 0, edgenz = 0;
    for (int i = threadIdx.x; i < 4096; i += 256) {
        unsigned int bits = ((unsigned int)wh[i]) << 16;
        float v = __uint_as_float(bits);
        if (!(fabsf(v) <= 100.0f)) badw = 1;         // NaN/Inf/huge -> fp32 backing
        if ((i & 1) == 1 && ei[i] != 0u) edgenz = 1; // odd word nonzero -> int32
    }
    if (badw)   atomicOr(&s_badw, 1);
    if (edgenz) atomicOr(&s_edgenz, 1);
    __syncthreads();
    if (threadIdx.x == 0) {
        flags[0] = s_badw ? 0 : 1;
        flags[1] = s_edgenz ? 0 : 1;
    }
}

__device__ __forceinline__ int ld_row(const int* __restrict__ edge, int e, int e64) {
    return e64 ? edge[2 * (size_t)e] : edge[e];
}
__device__ __forceinline__ int ld_col(const int* __restrict__ edge, int e, int e64) {
    return e64 ? edge[2 * ((size_t)GE + (size_t)e)] : edge[(size_t)GE + (size_t)e];
}
__device__ __forceinline__ float ld_f(const void* __restrict__ p, size_t i, int bf16f) {
    if (bf16f) return __bfloat162float(((const __hip_bfloat16*)p)[i]);
    return ((const float*)p)[i];
}

__device__ __forceinline__ float bf_lo(unsigned u) { return __uint_as_float(u << 16); }
__device__ __forceinline__ float bf_hi(unsigned u) { return __uint_as_float(u & 0xFFFF0000u); }
__device__ __forceinline__ unsigned bf16bits(float f) {
    __hip_bfloat16 h = __float2bfloat16(f);
    unsigned short s;
    __builtin_memcpy(&s, &h, 2);
    return (unsigned)s;
}

// ---- fused P1 (blocks 0..NG-1) + OUT-init (remaining blocks) ----
// P1: partition edges into NG col-group buckets (packed (c_local<<17)|r).
// init: OUT = bf16(alpha[0] * weight).  Independent work, one dispatch.
__global__ void p1init_kernel(const int* __restrict__ edge, const int* __restrict__ flags,
                              int* __restrict__ gcount, unsigned* __restrict__ bucket,
                              int E, int chunk,
                              const void* __restrict__ w, const void* __restrict__ alpha,
                              __hip_bfloat16* __restrict__ OUT, int nd) {
    if (blockIdx.x < NG) {
        __shared__ int cnt[NG];
        __shared__ int base[NG];
        int t = threadIdx.x;
        int e64 = flags[1];
        cnt[t] = 0;
        __syncthreads();
        int lo = blockIdx.x * chunk;
        int hiE = min(lo + chunk, E);
        // pass A: count valid edges per group
        for (int e = lo + t; e < hiE; e += 256) {
            int c = ld_col(edge, e, e64);
            int r = ld_row(edge, e, e64);
            if ((unsigned)c < (unsigned)GN && (unsigned)r < (unsigned)GN)
                atomicAdd(&cnt[c / CPG], 1);
        }
        __syncthreads();
        int cv = cnt[t];
        base[t] = (cv > 0) ? atomicAdd(&gcount[t], cv) : 0;
        __syncthreads();
        cnt[t] = 0;   // reuse as running offsets
        __syncthreads();
        // pass B: write entries (chunk is L2-hot from pass A)
        for (int e = lo + t; e < hiE; e += 256) {
            int c = ld_col(edge, e, e64);
            int r = ld_row(edge, e, e64);
            if ((unsigned)c < (unsigned)GN && (unsigned)r < (unsigned)GN) {
                int g = c / CPG;
                int idx = base[g] + atomicAdd(&cnt[g], 1);
                if (idx < CAP)
                    bucket[(size_t)g * CAP + idx] = ((unsigned)(c - g * CPG) << 17) | (unsigned)r;
            }
        }
    } else {
        int bid = blockIdx.x - NG;
        int i = 4 * (bid * 256 + (int)threadIdx.x);
        int wbf = flags[0];
        if (i < nd) {
            float a0 = ld_f(alpha, 0, wbf);
            float v0 = ld_f(w, i + 0, wbf);
            float v1 = ld_f(w, i + 1, wbf);
            float v2 = ld_f(w, i + 2, wbf);
            float v3 = ld_f(w, i + 3, wbf);
            uint2 q;
            q.x = (bf16bits(a0 * v1) << 16) | bf16bits(a0 * v0);
            q.y = (bf16bits(a0 * v3) << 16) | bf16bits(a0 * v2);
            *(uint2*)(OUT + i) = q;
        }
    }
}

// ---- P2: per group, self-scan gcount -> base; LDS hist -> dinv + rowptr + csr ----
__global__ void p2_kernel(const unsigned* __restrict__ bucket, const int* __restrict__ gcount,
                          int* __restrict__ rowptr, float* __restrict__ dinv,
                          int* __restrict__ csr) {
    int g = blockIdx.x;
    int t = threadIdx.x;
    __shared__ int gs[NG];
    __shared__ int hist[512];
    __shared__ int s[512];
    int gv = gcount[t]; if (gv > CAP) gv = CAP;
    gs[t] = gv;
    hist[t] = 0; hist[t + 256] = 0;
    __syncthreads();
    for (int off = 1; off < NG; off <<= 1) {
        int u = (t >= off) ? gs[t - off] : 0;
        __syncthreads();
        gs[t] += u;
        __syncthreads();
    }
    int mg = gcount[g]; if (mg > CAP) mg = CAP;
    int gb = gs[g] - mg;          // exclusive group base
    int m = mg;
    const unsigned* bk = bucket + (size_t)g * CAP;
    for (int idx = t; idx < m; idx += 256)
        atomicAdd(&hist[bk[idx] >> 17], 1);
    __syncthreads();
    int h0 = hist[t], h1 = hist[t + 256];
    s[t] = h0; s[t + 256] = h1;
    __syncthreads();
    for (int off = 1; off < 512; off <<= 1) {
        int v0 = (t >= off) ? s[t - off] : 0;
        int v1 = (t + 256 >= off) ? s[t + 256 - off] : 0;
        __syncthreads();
        s[t] += v0; s[t + 256] += v1;
        __syncthreads();
    }
    // s = inclusive scan; rowptr[col] = global END of segment
    int col0 = g * CPG + t;
    int col1 = col0 + 256;
    if (col0 < GN) {
        rowptr[col0] = gb + s[t];
        dinv[col0] = (h0 > 0) ? rsqrtf((float)h0) : 0.0f;
    }
    if (t + 256 < CPG && col1 < GN) {
        rowptr[col1] = gb + s[t + 256];
        dinv[col1] = (h1 > 0) ? rsqrtf((float)h1) : 0.0f;
    }
    __syncthreads();
    hist[t] = s[t] - h0;             // exclusive -> running counters
    hist[t + 256] = s[t + 256] - h1;
    __syncthreads();
    for (int idx = t; idx < m; idx += 256) {
        unsigned u = bk[idx];
        int cl = u >> 17;
        int r  = (int)(u & 0x1FFFFu);
        int pos = gb + atomicAdd(&hist[cl], 1);
        csr[pos] = r;
    }
}

// ---- source-row loader: bf16 row (uint2) or fp32 row (uint4), uniform branch ----
__device__ __forceinline__ float4 ld_xrow(const void* __restrict__ Xp, int r, int i, int asf32) {
    float4 o;
    if (asf32) {
        const float* p = (const float*)Xp + (size_t)r * GD + 4 * i;
        o.x = p[0]; o.y = p[1]; o.z = p[2]; o.w = p[3];
    } else {
        uint2 u = *(const uint2*)((const __hip_bfloat16*)Xp + (size_t)r * GD + 4 * i);
        o.x = bf_lo(u.x); o.y = bf_hi(u.x); o.z = bf_lo(u.y); o.w = bf_hi(u.y);
    }
    return o;
}

// ---- one hop, gather form, fused axpy; 4 edges/step (16 lanes x 8B),
// fully-predicated 16-edge block. Xsrc may be the raw weight input (hop 1):
// src_is_w selects fp32 row loads when weight is fp32. ----
__global__ void gather_kernel(const void* __restrict__ Xsrc,
                              __hip_bfloat16* __restrict__ Y,
                              __hip_bfloat16* __restrict__ OUT,
                              const int* __restrict__ rowptr, const int* __restrict__ csr,
                              const float* __restrict__ dinv,
                              const void* __restrict__ alpha, const int* __restrict__ flags,
                              int k, int store_y, int src_is_w, int N) {
    int t = blockIdx.x * blockDim.x + threadIdx.x;
    int node = __builtin_amdgcn_readfirstlane(t >> 6);
    if (node >= N) return;
    int lane = t & 63;
    int h = lane >> 4;        // edge slot within a 4-edge step
    int i = lane & 15;        // dim-quad index (dims 4i..4i+3)
    int asf32 = src_is_w && !flags[0];   // wave-uniform
    // independent early loads (hidden under the edge loop)
    int beg = node ? rowptr[node - 1] : 0;   // rowptr[c] = segment end
    int end = rowptr[node];
    float dc = dinv[node];
    float a = ld_f(alpha, k, flags[0]);
    size_t obase = (size_t)node * GD + 4 * i;
    uint2 uo = *(const uint2*)(OUT + obase);  // OUT row prefetch
    float f0 = 0.0f, f1 = 0.0f, f2 = 0.0f, f3 = 0.0f;
    for (int j = beg; j < end; j += 16) {
        int i0 = j + 0 + h;  int i1 = j + 4 + h;
        int i2 = j + 8 + h;  int i3 = j + 12 + h;
        int last = end - 1;
        int r0 = csr[min(i0, last)];
        int r1 = csr[min(i1, last)];
        int r2 = csr[min(i2, last)];
        int r3 = csr[min(i3, last)];
        float w0 = (i0 < end) ? dinv[r0] : 0.0f;
        float w1 = (i1 < end) ? dinv[r1] : 0.0f;
        float w2 = (i2 < end) ? dinv[r2] : 0.0f;
        float w3 = (i3 < end) ? dinv[r3] : 0.0f;
        float4 x0 = ld_xrow(Xsrc, r0, i, asf32);
        float4 x1 = ld_xrow(Xsrc, r1, i, asf32);
        float4 x2 = ld_xrow(Xsrc, r2, i, asf32);
        float4 x3 = ld_xrow(Xsrc, r3, i, asf32);
        f0 = fmaf(w0, x0.x, f0); f1 = fmaf(w0, x0.y, f1);
        f2 = fmaf(w0, x0.z, f2); f3 = fmaf(w0, x0.w, f3);
        f0 = fmaf(w1, x1.x, f0); f1 = fmaf(w1, x1.y, f1);
        f2 = fmaf(w1, x1.z, f2); f3 = fmaf(w1, x1.w, f3);
        f0 = fmaf(w2, x2.x, f0); f1 = fmaf(w2, x2.y, f1);
        f2 = fmaf(w2, x2.z, f2); f3 = fmaf(w2, x2.w, f3);
        f0 = fmaf(w3, x3.x, f0); f1 = fmaf(w3, x3.y, f1);
        f2 = fmaf(w3, x3.z, f2); f3 = fmaf(w3, x3.w, f3);
    }
    // combine the 4 edge slots (disjoint edge subsets)
    f0 += __shfl_xor(f0, 16, 64); f0 += __shfl_xor(f0, 32, 64);
    f1 += __shfl_xor(f1, 16, 64); f1 += __shfl_xor(f1, 32, 64);
    f2 += __shfl_xor(f2, 16, 64); f2 += __shfl_xor(f2, 32, 64);
    f3 += __shfl_xor(f3, 16, 64); f3 += __shfl_xor(f3, 32, 64);
    f0 *= dc; f1 *= dc; f2 *= dc; f3 *= dc;
    if (h == 0) {
        if (store_y) {
            uint2 p;
            p.x = (bf16bits(f1) << 16) | bf16bits(f0);
            p.y = (bf16bits(f3) << 16) | bf16bits(f2);
            *(uint2*)(Y + obase) = p;
        }
        float o0 = fmaf(a, f0, bf_lo(uo.x));
        float o1 = fmaf(a, f1, bf_hi(uo.x));
        float o2 = fmaf(a, f2, bf_lo(uo.y));
        float o3 = fmaf(a, f3, bf_hi(uo.y));
        uint2 q;
        q.x = (bf16bits(o1) << 16) | bf16bits(o0);
        q.y = (bf16bits(o3) << 16) | bf16bits(o2);
        *(uint2*)(OUT + obase) = q;
    }
}

// ---- bf16-pair dot helper ----
__device__ __forceinline__ float dot2_bf16(unsigned ua, unsigned ub) {
    return fmaf(bf_lo(ua), bf_lo(ub), bf_hi(ua) * bf_hi(ub));
}

// ---- res[e] = dot(OUT[row[e]], OUT[col[e]]) — 4 threads/edge, 2x16B per row ----
__global__ void dot_kernel(const __hip_bfloat16* __restrict__ OUT,
                           const int* __restrict__ edge, const int* __restrict__ flags,
                           void* __restrict__ res, int E) {
    int t = blockIdx.x * blockDim.x + threadIdx.x;
    int e = t >> 2;
    int sub = t & 3;
    if (e >= E) return;
    int e64 = flags[1];
    int wbf = flags[0];
    int r = ld_row(edge, e, e64);
    int c = ld_col(edge, e, e64);
    float p = 0.0f;
    if ((unsigned)r < (unsigned)GN && (unsigned)c < (unsigned)GN) {
        const uint4* pa = (const uint4*)(OUT + (size_t)r * GD + sub * 16);
        const uint4* pb = (const uint4*)(OUT + (size_t)c * GD + sub * 16);
        uint4 a0 = pa[0], a1 = pa[1];
        uint4 b0 = pb[0], b1 = pb[1];
        p = ((dot2_bf16(a0.x, b0.x) + dot2_bf16(a0.y, b0.y)) +
             (dot2_bf16(a0.z, b0.z) + dot2_bf16(a0.w, b0.w))) +
            ((dot2_bf16(a1.x, b1.x) + dot2_bf16(a1.y, b1.y)) +
             (dot2_bf16(a1.z, b1.z) + dot2_bf16(a1.w, b1.w)));
    }
    p += __shfl_down(p, 2, 4);
    p += __shfl_down(p, 1, 4);
    if (sub == 0) {
        if (wbf) ((__hip_bfloat16*)res)[e] = __float2bfloat16(p);
        else     ((float*)res)[e] = p;
    }
}

extern "C" void kernel_launch(void* const* d_in, const int* in_sizes, int n_in,
                              void* d_out, int out_size, void* d_ws, size_t ws_size,
                              hipStream_t stream) {
    const int E = GE, N = GN, ND = GN * GD;

    const void* edge   = d_in[0];
    const void* weight = d_in[1];
    const void* alpha  = d_in[2];

    // Workspace layout (~38 MB total)
    char* ws = (char*)d_ws;
    int*      flags     = (int*)ws;      ws += 256;
    int*      gcount    = (int*)ws;      ws += 1024;
    float*    dinv      = (float*)ws;    ws += (((size_t)N * 4 + 255) / 256) * 256;
    int*      rowptr    = (int*)ws;      ws += (((size_t)N * 4 + 255) / 256) * 256;
    unsigned* bucket    = (unsigned*)ws; ws += (size_t)NG * CAP * 4;   // 6.3 MB
    int*      csr       = (int*)ws;      ws += (size_t)E * 4;          // 4.8 MB
    __hip_bfloat16* Y   = (__hip_bfloat16*)ws; ws += (size_t)ND * 2;   // 12.8 MB (hop1/3 out)
    __hip_bfloat16* X2  = (__hip_bfloat16*)ws; ws += (size_t)ND * 2;   // 12.8 MB (hop2 out)
    __hip_bfloat16* OUT = (__hip_bfloat16*)ws; ws += (size_t)ND * 2;   // 12.8 MB

    const int B = 256;

    detect_kernel<<<1, 256, 0, stream>>>(weight, edge, flags, gcount);

    // fused: radix partition (blocks 0..255) + OUT init (remaining blocks)
    {
        const int chunk = (E + NG - 1) / NG;      // 4688
        const int initBlocks = (ND / 4 + B - 1) / B;  // 6250
        p1init_kernel<<<NG + initBlocks, B, 0, stream>>>(
            (const int*)edge, flags, gcount, bucket, E, chunk,
            weight, alpha, OUT, ND);
    }
    p2_kernel<<<NG, 256, 0, stream>>>(bucket, gcount, rowptr, dinv, csr);

    // 3 propagation hops; hop 1 gathers straight from the weight input
    const int ggrid = (int)(((size_t)N * 64 + B - 1) / B);
    gather_kernel<<<ggrid, B, 0, stream>>>(weight, Y, OUT, rowptr, csr, dinv, alpha, flags, 1, 1, 1, N);
    gather_kernel<<<ggrid, B, 0, stream>>>(Y, X2, OUT, rowptr, csr, dinv, alpha, flags, 2, 1, 0, N);
    gather_kernel<<<ggrid, B, 0, stream>>>(X2, Y, OUT, rowptr, csr, dinv, alpha, flags, 3, 0, 0, N);

    // per-edge link scores (4 threads/edge, 2x uint4 per row)
    dot_kernel<<<(int)(((size_t)E * 4 + B - 1) / B), B, 0, stream>>>(OUT, (const int*)edge, flags, d_out, E);
}

// Round 14
// 275.104 us; speedup vs baseline: 1.1620x; 1.1620x over previous
//
#include <hip/hip_runtime.h>
#include <hip/hip_bf16.h>

// Problem constants: N=100000 nodes, E=1200000 edges, D=64, K=3 hops.
#define GN 100000
#define GE 1200000
#define GD 64
#define NG 256                 // col groups
#define CPG 391                // cols per group (256*391 = 100096 >= GN)
#define CAP 6144               // bucket capacity per group (mean 4688, std 68)

// ws_size ~256 MB (observed). This layout uses ~51 MB.
//
// History (see git log): r11 radix-partition CSR build; r12 predicated
// 16-edge gather blocks (45.7 us/hop, FETCH 73 MB); r13 REGRESSION: a
// runtime-branch row loader (bf16 vs fp32) was if-converted by the compiler
// -> BOTH loads issued every iter -> FETCH doubled to 147 MB. Lesson: no
// runtime dtype branches in hot loops; keep gather bf16-only and convert
// once in init. r14 = r12 gather + r13's p1+init fusion (init writes X+OUT).

// ---------------------------------------------------------------------------
// Runtime dtype detection. flags[0]=1 if weight/alpha bf16 else fp32.
// flags[1]=1 if edge_index int64 else int32.  Also zeroes gcount.
// ---------------------------------------------------------------------------
__global__ void detect_kernel(const void* __restrict__ w,
                              const void* __restrict__ edge,
                              int* __restrict__ flags, int* __restrict__ gcount) {
    __shared__ int s_badw, s_edgenz;
    if (threadIdx.x == 0) { s_badw = 0; s_edgenz = 0; }
    gcount[threadIdx.x] = 0;
    __syncthreads();
    const unsigned short* wh = (const unsigned short*)w;
    const unsigned int*   ei = (const unsigned int*)edge;
    int badw = 0, edgenz = 0;
    for (int i = threadIdx.x; i < 4096; i += 256) {
        unsigned int bits = ((unsigned int)wh[i]) << 16;
        float v = __uint_as_float(bits);
        if (!(fabsf(v) <= 100.0f)) badw = 1;         // NaN/Inf/huge -> fp32 backing
        if ((i & 1) == 1 && ei[i] != 0u) edgenz = 1; // odd word nonzero -> int32
    }
    if (badw)   atomicOr(&s_badw, 1);
    if (edgenz) atomicOr(&s_edgenz, 1);
    __syncthreads();
    if (threadIdx.x == 0) {
        flags[0] = s_badw ? 0 : 1;
        flags[1] = s_edgenz ? 0 : 1;
    }
}

__device__ __forceinline__ int ld_row(const int* __restrict__ edge, int e, int e64) {
    return e64 ? edge[2 * (size_t)e] : edge[e];
}
__device__ __forceinline__ int ld_col(const int* __restrict__ edge, int e, int e64) {
    return e64 ? edge[2 * ((size_t)GE + (size_t)e)] : edge[(size_t)GE + (size_t)e];
}
__device__ __forceinline__ float ld_f(const void* __restrict__ p, size_t i, int bf16f) {
    if (bf16f) return __bfloat162float(((const __hip_bfloat16*)p)[i]);
    return ((const float*)p)[i];
}

__device__ __forceinline__ float bf_lo(unsigned u) { return __uint_as_float(u << 16); }
__device__ __forceinline__ float bf_hi(unsigned u) { return __uint_as_float(u & 0xFFFF0000u); }
__device__ __forceinline__ unsigned bf16bits(float f) {
    __hip_bfloat16 h = __float2bfloat16(f);
    unsigned short s;
    __builtin_memcpy(&s, &h, 2);
    return (unsigned)s;
}

// ---- fused P1 (blocks 0..NG-1) + X/OUT-init (remaining blocks) ----
// P1: partition edges into NG col-group buckets (packed (c_local<<17)|r).
// init: X = bf16(weight); OUT = bf16(alpha[0] * weight). One dispatch.
__global__ void p1init_kernel(const int* __restrict__ edge, const int* __restrict__ flags,
                              int* __restrict__ gcount, unsigned* __restrict__ bucket,
                              int E, int chunk,
                              const void* __restrict__ w, const void* __restrict__ alpha,
                              __hip_bfloat16* __restrict__ X,
                              __hip_bfloat16* __restrict__ OUT, int nd) {
    if (blockIdx.x < NG) {
        __shared__ int cnt[NG];
        __shared__ int base[NG];
        int t = threadIdx.x;
        int e64 = flags[1];
        cnt[t] = 0;
        __syncthreads();
        int lo = blockIdx.x * chunk;
        int hiE = min(lo + chunk, E);
        // pass A: count valid edges per group
        for (int e = lo + t; e < hiE; e += 256) {
            int c = ld_col(edge, e, e64);
            int r = ld_row(edge, e, e64);
            if ((unsigned)c < (unsigned)GN && (unsigned)r < (unsigned)GN)
                atomicAdd(&cnt[c / CPG], 1);
        }
        __syncthreads();
        int cv = cnt[t];
        base[t] = (cv > 0) ? atomicAdd(&gcount[t], cv) : 0;
        __syncthreads();
        cnt[t] = 0;   // reuse as running offsets
        __syncthreads();
        // pass B: write entries (chunk is L2-hot from pass A)
        for (int e = lo + t; e < hiE; e += 256) {
            int c = ld_col(edge, e, e64);
            int r = ld_row(edge, e, e64);
            if ((unsigned)c < (unsigned)GN && (unsigned)r < (unsigned)GN) {
                int g = c / CPG;
                int idx = base[g] + atomicAdd(&cnt[g], 1);
                if (idx < CAP)
                    bucket[(size_t)g * CAP + idx] = ((unsigned)(c - g * CPG) << 17) | (unsigned)r;
            }
        }
    } else {
        int bid = blockIdx.x - NG;
        int i = 4 * (bid * 256 + (int)threadIdx.x);
        int wbf = flags[0];
        if (i < nd) {
            float a0 = ld_f(alpha, 0, wbf);
            float v0 = ld_f(w, i + 0, wbf);
            float v1 = ld_f(w, i + 1, wbf);
            float v2 = ld_f(w, i + 2, wbf);
            float v3 = ld_f(w, i + 3, wbf);
            uint2 xq;
            xq.x = (bf16bits(v1) << 16) | bf16bits(v0);
            xq.y = (bf16bits(v3) << 16) | bf16bits(v2);
            *(uint2*)(X + i) = xq;
            uint2 oq;
            oq.x = (bf16bits(a0 * v1) << 16) | bf16bits(a0 * v0);
            oq.y = (bf16bits(a0 * v3) << 16) | bf16bits(a0 * v2);
            *(uint2*)(OUT + i) = oq;
        }
    }
}

// ---- P2: per group, self-scan gcount -> base; LDS hist -> dinv + rowptr + csr ----
__global__ void p2_kernel(const unsigned* __restrict__ bucket, const int* __restrict__ gcount,
                          int* __restrict__ rowptr, float* __restrict__ dinv,
                          int* __restrict__ csr) {
    int g = blockIdx.x;
    int t = threadIdx.x;
    __shared__ int gs[NG];
    __shared__ int hist[512];
    __shared__ int s[512];
    int gv = gcount[t]; if (gv > CAP) gv = CAP;
    gs[t] = gv;
    hist[t] = 0; hist[t + 256] = 0;
    __syncthreads();
    for (int off = 1; off < NG; off <<= 1) {
        int u = (t >= off) ? gs[t - off] : 0;
        __syncthreads();
        gs[t] += u;
        __syncthreads();
    }
    int mg = gcount[g]; if (mg > CAP) mg = CAP;
    int gb = gs[g] - mg;          // exclusive group base
    int m = mg;
    const unsigned* bk = bucket + (size_t)g * CAP;
    for (int idx = t; idx < m; idx += 256)
        atomicAdd(&hist[bk[idx] >> 17], 1);
    __syncthreads();
    int h0 = hist[t], h1 = hist[t + 256];
    s[t] = h0; s[t + 256] = h1;
    __syncthreads();
    for (int off = 1; off < 512; off <<= 1) {
        int v0 = (t >= off) ? s[t - off] : 0;
        int v1 = (t + 256 >= off) ? s[t + 256 - off] : 0;
        __syncthreads();
        s[t] += v0; s[t + 256] += v1;
        __syncthreads();
    }
    // s = inclusive scan; rowptr[col] = global END of segment
    int col0 = g * CPG + t;
    int col1 = col0 + 256;
    if (col0 < GN) {
        rowptr[col0] = gb + s[t];
        dinv[col0] = (h0 > 0) ? rsqrtf((float)h0) : 0.0f;
    }
    if (t + 256 < CPG && col1 < GN) {
        rowptr[col1] = gb + s[t + 256];
        dinv[col1] = (h1 > 0) ? rsqrtf((float)h1) : 0.0f;
    }
    __syncthreads();
    hist[t] = s[t] - h0;             // exclusive -> running counters
    hist[t + 256] = s[t + 256] - h1;
    __syncthreads();
    for (int idx = t; idx < m; idx += 256) {
        unsigned u = bk[idx];
        int cl = u >> 17;
        int r  = (int)(u & 0x1FFFFu);
        int pos = gb + atomicAdd(&hist[cl], 1);
        csr[pos] = r;
    }
}

// ---- one hop, gather form, fused axpy; 4 edges/step (16 lanes x uint2),
// fully-predicated 16-edge block (r12 structure — bf16-only loads, NO
// runtime dtype branch in the loop). ----
__global__ void gather_kernel(const __hip_bfloat16* __restrict__ X,
                              __hip_bfloat16* __restrict__ Y,
                              __hip_bfloat16* __restrict__ OUT,
                              const int* __restrict__ rowptr, const int* __restrict__ csr,
                              const float* __restrict__ dinv,
                              const void* __restrict__ alpha, const int* __restrict__ flags,
                              int k, int store_y, int N) {
    int t = blockIdx.x * blockDim.x + threadIdx.x;
    int node = __builtin_amdgcn_readfirstlane(t >> 6);
    if (node >= N) return;
    int lane = t & 63;
    int h = lane >> 4;        // edge slot within a 4-edge step
    int i = lane & 15;        // dim-quad index (dims 4i..4i+3)
    // independent early loads (hidden under the edge loop)
    int beg = node ? rowptr[node - 1] : 0;   // rowptr[c] = segment end
    int end = rowptr[node];
    float dc = dinv[node];
    float a = ld_f(alpha, k, flags[0]);
    size_t obase = (size_t)node * GD + 4 * i;
    uint2 uo = *(const uint2*)(OUT + obase);  // OUT row prefetch
    float f0 = 0.0f, f1 = 0.0f, f2 = 0.0f, f3 = 0.0f;
    for (int j = beg; j < end; j += 16) {
        int i0 = j + 0 + h;  int i1 = j + 4 + h;
        int i2 = j + 8 + h;  int i3 = j + 12 + h;
        int last = end - 1;
        int r0 = csr[min(i0, last)];
        int r1 = csr[min(i1, last)];
        int r2 = csr[min(i2, last)];
        int r3 = csr[min(i3, last)];
        float w0 = (i0 < end) ? dinv[r0] : 0.0f;
        float w1 = (i1 < end) ? dinv[r1] : 0.0f;
        float w2 = (i2 < end) ? dinv[r2] : 0.0f;
        float w3 = (i3 < end) ? dinv[r3] : 0.0f;
        uint2 u0 = *(const uint2*)(X + (size_t)r0 * GD + 4 * i);
        uint2 u1 = *(const uint2*)(X + (size_t)r1 * GD + 4 * i);
        uint2 u2 = *(const uint2*)(X + (size_t)r2 * GD + 4 * i);
        uint2 u3 = *(const uint2*)(X + (size_t)r3 * GD + 4 * i);
        f0 = fmaf(w0, bf_lo(u0.x), f0); f1 = fmaf(w0, bf_hi(u0.x), f1);
        f2 = fmaf(w0, bf_lo(u0.y), f2); f3 = fmaf(w0, bf_hi(u0.y), f3);
        f0 = fmaf(w1, bf_lo(u1.x), f0); f1 = fmaf(w1, bf_hi(u1.x), f1);
        f2 = fmaf(w1, bf_lo(u1.y), f2); f3 = fmaf(w1, bf_hi(u1.y), f3);
        f0 = fmaf(w2, bf_lo(u2.x), f0); f1 = fmaf(w2, bf_hi(u2.x), f1);
        f2 = fmaf(w2, bf_lo(u2.y), f2); f3 = fmaf(w2, bf_hi(u2.y), f3);
        f0 = fmaf(w3, bf_lo(u3.x), f0); f1 = fmaf(w3, bf_hi(u3.x), f1);
        f2 = fmaf(w3, bf_lo(u3.y), f2); f3 = fmaf(w3, bf_hi(u3.y), f3);
    }
    // combine the 4 edge slots (disjoint edge subsets)
    f0 += __shfl_xor(f0, 16, 64); f0 += __shfl_xor(f0, 32, 64);
    f1 += __shfl_xor(f1, 16, 64); f1 += __shfl_xor(f1, 32, 64);
    f2 += __shfl_xor(f2, 16, 64); f2 += __shfl_xor(f2, 32, 64);
    f3 += __shfl_xor(f3, 16, 64); f3 += __shfl_xor(f3, 32, 64);
    f0 *= dc; f1 *= dc; f2 *= dc; f3 *= dc;
    if (h == 0) {
        if (store_y) {
            uint2 p;
            p.x = (bf16bits(f1) << 16) | bf16bits(f0);
            p.y = (bf16bits(f3) << 16) | bf16bits(f2);
            *(uint2*)(Y + obase) = p;
        }
        float o0 = fmaf(a, f0, bf_lo(uo.x));
        float o1 = fmaf(a, f1, bf_hi(uo.x));
        float o2 = fmaf(a, f2, bf_lo(uo.y));
        float o3 = fmaf(a, f3, bf_hi(uo.y));
        uint2 q;
        q.x = (bf16bits(o1) << 16) | bf16bits(o0);
        q.y = (bf16bits(o3) << 16) | bf16bits(o2);
        *(uint2*)(OUT + obase) = q;
    }
}

// ---- bf16-pair dot helper ----
__device__ __forceinline__ float dot2_bf16(unsigned ua, unsigned ub) {
    return fmaf(bf_lo(ua), bf_lo(ub), bf_hi(ua) * bf_hi(ub));
}

// ---- res[e] = dot(OUT[row[e]], OUT[col[e]]) — 4 threads/edge, 2x16B per row ----
__global__ void dot_kernel(const __hip_bfloat16* __restrict__ OUT,
                           const int* __restrict__ edge, const int* __restrict__ flags,
                           void* __restrict__ res, int E) {
    int t = blockIdx.x * blockDim.x + threadIdx.x;
    int e = t >> 2;
    int sub = t & 3;
    if (e >= E) return;
    int e64 = flags[1];
    int wbf = flags[0];
    int r = ld_row(edge, e, e64);
    int c = ld_col(edge, e, e64);
    float p = 0.0f;
    if ((unsigned)r < (unsigned)GN && (unsigned)c < (unsigned)GN) {
        const uint4* pa = (const uint4*)(OUT + (size_t)r * GD + sub * 16);
        const uint4* pb = (const uint4*)(OUT + (size_t)c * GD + sub * 16);
        uint4 a0 = pa[0], a1 = pa[1];
        uint4 b0 = pb[0], b1 = pb[1];
        p = ((dot2_bf16(a0.x, b0.x) + dot2_bf16(a0.y, b0.y)) +
             (dot2_bf16(a0.z, b0.z) + dot2_bf16(a0.w, b0.w))) +
            ((dot2_bf16(a1.x, b1.x) + dot2_bf16(a1.y, b1.y)) +
             (dot2_bf16(a1.z, b1.z) + dot2_bf16(a1.w, b1.w)));
    }
    p += __shfl_down(p, 2, 4);
    p += __shfl_down(p, 1, 4);
    if (sub == 0) {
        if (wbf) ((__hip_bfloat16*)res)[e] = __float2bfloat16(p);
        else     ((float*)res)[e] = p;
    }
}

extern "C" void kernel_launch(void* const* d_in, const int* in_sizes, int n_in,
                              void* d_out, int out_size, void* d_ws, size_t ws_size,
                              hipStream_t stream) {
    const int E = GE, N = GN, ND = GN * GD;

    const void* edge   = d_in[0];
    const void* weight = d_in[1];
    const void* alpha  = d_in[2];

    // Workspace layout (~51 MB total)
    char* ws = (char*)d_ws;
    int*      flags     = (int*)ws;      ws += 256;
    int*      gcount    = (int*)ws;      ws += 1024;
    float*    dinv      = (float*)ws;    ws += (((size_t)N * 4 + 255) / 256) * 256;
    int*      rowptr    = (int*)ws;      ws += (((size_t)N * 4 + 255) / 256) * 256;
    unsigned* bucket    = (unsigned*)ws; ws += (size_t)NG * CAP * 4;   // 6.3 MB
    int*      csr       = (int*)ws;      ws += (size_t)E * 4;          // 4.8 MB
    __hip_bfloat16* X   = (__hip_bfloat16*)ws; ws += (size_t)ND * 2;   // 12.8 MB
    __hip_bfloat16* Y   = (__hip_bfloat16*)ws; ws += (size_t)ND * 2;   // 12.8 MB
    __hip_bfloat16* OUT = (__hip_bfloat16*)ws; ws += (size_t)ND * 2;   // 12.8 MB

    const int B = 256;

    detect_kernel<<<1, 256, 0, stream>>>(weight, edge, flags, gcount);

    // fused: radix partition (blocks 0..255) + X/OUT init (remaining blocks)
    {
        const int chunk = (E + NG - 1) / NG;          // 4688
        const int initBlocks = (ND / 4 + B - 1) / B;  // 6250
        p1init_kernel<<<NG + initBlocks, B, 0, stream>>>(
            (const int*)edge, flags, gcount, bucket, E, chunk,
            weight, alpha, X, OUT, ND);
    }
    p2_kernel<<<NG, 256, 0, stream>>>(bucket, gcount, rowptr, dinv, csr);

    // 3 propagation hops (r12 gather: bf16-only loads)
    const int ggrid = (int)(((size_t)N * 64 + B - 1) / B);
    gather_kernel<<<ggrid, B, 0, stream>>>(X, Y, OUT, rowptr, csr, dinv, alpha, flags, 1, 1, N);
    gather_kernel<<<ggrid, B, 0, stream>>>(Y, X, OUT, rowptr, csr, dinv, alpha, flags, 2, 1, N);
    gather_kernel<<<ggrid, B, 0, stream>>>(X, Y, OUT, rowptr, csr, dinv, alpha, flags, 3, 0, N);

    // per-edge link scores (4 threads/edge, 2x uint4 per row)
    dot_kernel<<<(int)(((size_t)E * 4 + B - 1) / B), B, 0, stream>>>(OUT, (const int*)edge, flags, d_out, E);
}